// Round 8
// baseline (2204.410 us; speedup 1.0000x reference)
//
#include <hip/hip_runtime.h>

#define NPTS    1024
#define DIM     16
#define GRAPHS  64
#define NITERS  20
#define THREADS 1024
#define NWAVES  (THREADS / 64)
#define RT      4        // 16-row tiles per wave (16 waves x 64 rows)
#define NCHUNK  16       // 64 j-tiles, 4 per chunk
#define WIN     100.0f   // prune window (log2 units) after warm-up
#define NWARM   4        // iterations with pruning disabled (exact trajectory)

typedef __bf16 bf16x8 __attribute__((ext_vector_type(8)));
typedef __bf16 bf16x4 __attribute__((ext_vector_type(4)));
typedef float  f32x4  __attribute__((ext_vector_type(4)));

#define KLOG 577.07801635558536f      // log2(e)/eps, eps = 0.05^2
#define CLSE 0.0017328679513998633f   // eps*ln2   (KLOG*CLSE == 1)

static __device__ __forceinline__ float fexp2(float x){ return __builtin_amdgcn_exp2f(x); }
static __device__ __forceinline__ float flog2(float x){ return __builtin_amdgcn_logf(x); }

// global f32 cloud -> LDS split-bf16 (hi, lo), optionally pre-scaled
static __device__ __forceinline__ void split_store(
    __bf16* __restrict__ dh, __bf16* __restrict__ dl,
    const float* __restrict__ src, const float scale, const int tid)
{
    const float4* s4 = (const float4*)src;
    #pragma unroll 1
    for (int k = 0; k < (NPTS * DIM / 4) / THREADS; ++k) {
        const int idx = tid + k * THREADS;
        const float4 v = s4[idx];
        const float f0 = v.x * scale, f1 = v.y * scale,
                    f2 = v.z * scale, f3 = v.w * scale;
        bf16x4 h, l;
        h[0] = (__bf16)f0; l[0] = (__bf16)(f0 - (float)h[0]);
        h[1] = (__bf16)f1; l[1] = (__bf16)(f1 - (float)h[1]);
        h[2] = (__bf16)f2; l[2] = (__bf16)(f2 - (float)h[2]);
        h[3] = (__bf16)f3; l[3] = (__bf16)(f3 - (float)h[3]);
        *(bf16x4*)(dh + idx * 4) = h;
        *(bf16x4*)(dl + idx * 4) = l;
    }
}

// One half-iteration, SINGLE fused sweep with carried per-row baselines:
//   mr[row] seeded from sM (previous pass's lse for these rows).
//   acc = (t_j - mr) + dot; prune tile if all acc < -win; rare fixup branch
//   raises mr wave-uniformly when acc exceeds baseline (+1).
// Returns sum of row-LSEs (x16 column-lane dup); writes -10-lse to sB and
// lse to sM.
static __device__ __forceinline__ float sink_pass(
    const __bf16* __restrict__ rH, const __bf16* __restrict__ rL,
    const __bf16* __restrict__ cH, const __bf16* __restrict__ cL,
    float* __restrict__ sB, float* __restrict__ sM,
    const int wbase, const int lane, const float win)
{
    const int g  = lane >> 4;
    const int n  = lane & 15;
    const int gh = g & 1;

    // A fragments: [row-hi | row-lo] along K=32 (rows pre-scaled by KLOG)
    bf16x8 A[RT];
    {
        const __bf16* ap = (g < 2 ? rH : rL) + (wbase + n) * DIM + gh * 8;
        #pragma unroll
        for (int rt = 0; rt < RT; ++rt)
            A[rt] = *(const bf16x8*)(ap + rt * (16 * DIM));
    }

    // baselines (identical across the 16 column-lanes of each g-group)
    float mr[RT][4], s[RT][4];
    #pragma unroll
    for (int rt = 0; rt < RT; ++rt) {
        const f32x4 v = *(const f32x4*)(sM + wbase + rt * 16 + g * 4);
        #pragma unroll
        for (int e = 0; e < 4; ++e) { mr[rt][e] = v[e]; s[rt][e] = 0.0f; }
    }

    const __bf16* b1p = cH + n * DIM + gh * 8;   // [yh | yh]
    const __bf16* b2p = cL + n * DIM + gh * 8;   // [yl | yl]
    const float*  tp  = sB + n;

    #pragma unroll 1
    for (int c = 0; c < NCHUNK; ++c) {
        float t[4];
        #pragma unroll
        for (int q = 0; q < 4; ++q) t[q] = tp[c * 64 + q * 16];
        const int off = c * (4 * 16 * DIM);
        #pragma unroll
        for (int qq = 0; qq < 2; ++qq) {
            bf16x8 B1[2], B2[2];
            B1[0] = *(const bf16x8*)(b1p + off + (qq * 2 + 0) * (16 * DIM));
            B1[1] = *(const bf16x8*)(b1p + off + (qq * 2 + 1) * (16 * DIM));
            B2[0] = *(const bf16x8*)(b2p + off + (qq * 2 + 0) * (16 * DIM));
            B2[1] = *(const bf16x8*)(b2p + off + (qq * 2 + 1) * (16 * DIM));
            #pragma unroll
            for (int rt = 0; rt < RT; ++rt) {
                #pragma unroll
                for (int p = 0; p < 2; ++p) {
                    const float tq = t[qq * 2 + p];
                    f32x4 acc = { tq - mr[rt][0], tq - mr[rt][1],
                                  tq - mr[rt][2], tq - mr[rt][3] };
                    acc = __builtin_amdgcn_mfma_f32_16x16x32_bf16(A[rt], B2[p], acc, 0, 0, 0);
                    acc = __builtin_amdgcn_mfma_f32_16x16x32_bf16(A[rt], B1[p], acc, 0, 0, 0);
                    const float h = fmaxf(fmaxf(acc[0], acc[1]),
                                          fmaxf(acc[2], acc[3]));
                    if (__any(h > 1.0f)) {
                        // rare: baseline exceeded -> raise mr wave-uniformly
                        #pragma unroll
                        for (int e = 0; e < 4; ++e) {
                            float cm = acc[e];
                            cm = fmaxf(cm, __shfl_xor(cm, 1, 64));
                            cm = fmaxf(cm, __shfl_xor(cm, 2, 64));
                            cm = fmaxf(cm, __shfl_xor(cm, 4, 64));
                            cm = fmaxf(cm, __shfl_xor(cm, 8, 64));
                            const float sh = fmaxf(cm, 0.0f);
                            s[rt][e] = fmaf(s[rt][e], fexp2(-sh),
                                            fexp2(acc[e] - sh));
                            mr[rt][e] += sh;
                        }
                    } else if (__any(h > -win)) {
                        s[rt][0] += fexp2(acc[0]);
                        s[rt][1] += fexp2(acc[1]);
                        s[rt][2] += fexp2(acc[2]);
                        s[rt][3] += fexp2(acc[3]);
                    }
                }
            }
        }
    }

    // merge sums across the 16 column-class lanes (baselines identical)
    float lsum = 0.0f;
    float lse[RT][4];
    #pragma unroll
    for (int rt = 0; rt < RT; ++rt) {
        #pragma unroll
        for (int e = 0; e < 4; ++e) {
            float ss = s[rt][e];
            ss += __shfl_xor(ss, 1, 64);
            ss += __shfl_xor(ss, 2, 64);
            ss += __shfl_xor(ss, 4, 64);
            ss += __shfl_xor(ss, 8, 64);
            ss = fmaxf(ss, 1.0e-30f);        // no -inf propagation
            const float l = mr[rt][e] + flog2(ss);
            lsum += l;
            lse[rt][e] = l;
        }
    }

    __syncthreads();     // all reads of sB/sM complete block-wide
    if (n == 0) {
        #pragma unroll
        for (int rt = 0; rt < RT; ++rt) {
            const int row4 = wbase + rt * 16 + g * 4;
            f32x4 mv = { -10.0f - lse[rt][0], -10.0f - lse[rt][1],
                         -10.0f - lse[rt][2], -10.0f - lse[rt][3] };
            f32x4 lv = { lse[rt][0], lse[rt][1], lse[rt][2], lse[rt][3] };
            *(f32x4*)(sB + row4) = mv;
            *(f32x4*)(sM + row4) = lv;
        }
    }
    __syncthreads();
    return lsum;
}

__global__ __launch_bounds__(THREADS)
void sinkhorn_kernel(const float* __restrict__ xg,
                     const float* __restrict__ yg,
                     float* __restrict__ out)
{
    extern __shared__ char ldsraw[];
    __bf16* sxh = (__bf16*)ldsraw;              // [1024][16] hi of K*x
    __bf16* sxl = sxh + NPTS * DIM;             // lo of K*x
    __bf16* syh = sxl + NPTS * DIM;             // hi of y
    __bf16* syl = syh + NPTS * DIM;             // lo of y
    float*  sB  = (float*)(syl + NPTS * DIM);   // [1024] messages (log2 units)
    float*  sMf = sB + NPTS;                    // [1024] stale lse, f-rows
    float*  sMg = sMf + NPTS;                   // [1024] stale lse, g-rows

    const int tid   = threadIdx.x;
    const int lane  = tid & 63;
    const int wave  = tid >> 6;
    const int wbase = wave * (RT * 16);

    const int graph = blockIdx.x / 3;
    const int term  = blockIdx.x - graph * 3;   // 0:(x,y) 1:(x,x) 2:(y,y)
    const float* xb = xg + (size_t)graph * (NPTS * DIM);
    const float* yb = yg + (size_t)graph * (NPTS * DIM);
    const float* Xp = (term == 2) ? yb : xb;
    const float* Yp = (term == 1) ? xb : yb;

    split_store(sxh, sxl, Xp, KLOG, tid);       // row side carries the 1/eps scale
    split_store(syh, syl, Yp, 1.0f, tid);

    // prologue (thread = row): quadratic terms, message init, baseline seeds
    float csum;
    {
        const float4* xr = (const float4*)(Xp + tid * DIM);
        const float4* yr = (const float4*)(Yp + tid * DIM);
        float hx = 0.0f, hy = 0.0f, d = 0.0f;
        #pragma unroll
        for (int c = 0; c < 4; ++c) {
            const float4 a = xr[c], b = yr[c];
            hx = fmaf(a.x, a.x, hx); hx = fmaf(a.y, a.y, hx);
            hx = fmaf(a.z, a.z, hx); hx = fmaf(a.w, a.w, hx);
            hy = fmaf(b.x, b.x, hy); hy = fmaf(b.y, b.y, hy);
            hy = fmaf(b.z, b.z, hy); hy = fmaf(b.w, b.w, hy);
            d  = fmaf(a.x, b.x, d);  d  = fmaf(a.y, b.y, d);
            d  = fmaf(a.z, b.z, d);  d  = fmaf(a.w, b.w, d);
        }
        hx *= 0.5f; hy *= 0.5f;
        csum = hx + hy;
        sB[tid]  = fmaf(-KLOG, hy, -10.0f);          // t_j for g = 0
        sMf[tid] = fmaf(KLOG, d - hy, -10.0f);       // underestimate of f-pass-0 max
        sMg[tid] = fmaf(KLOG, d - hx, -10.0f);       // underestimate of g-pass-0 max
    }
    __syncthreads();

    float fsum = 0.0f, gsum = 0.0f;
    #pragma unroll 1
    for (int it = 0; it < NITERS; ++it) {
        const float w = (it < NWARM) ? 1.0e30f : WIN;   // warm: exact (no prune)
        fsum = sink_pass(sxh, sxl, syh, syl, sB, sMf, wbase, lane, w);  // f
        gsum = sink_pass(syh, syl, sxh, sxl, sB, sMg, wbase, lane, w);  // g
    }
    fsum = sink_pass(sxh, sxl, syh, syl, sB, sMf, wbase, lane, WIN);    // final f

    // OT = [csum - CLSE*(sum lse_f + sum lse_g)] / NPTS  (lse sums x16 dup)
    float v = fmaf(-CLSE, (fsum + gsum) * (1.0f / 16.0f), csum);
    #pragma unroll
    for (int off = 32; off; off >>= 1) v += __shfl_down(v, off, 64);
    if (lane == 0) sB[wave] = v;
    __syncthreads();
    if (tid == 0) {
        float tot = 0.0f;
        #pragma unroll
        for (int w = 0; w < NWAVES; ++w) tot += sB[w];
        const float wgt = ((term == 0) ? 1.0f : -0.5f)
                          / ((float)GRAPHS * (float)NPTS);
        atomicAdd(out, wgt * tot);
    }
}

extern "C" void kernel_launch(void* const* d_in, const int* in_sizes, int n_in,
                              void* d_out, int out_size, void* d_ws, size_t ws_size,
                              hipStream_t stream)
{
    (void)in_sizes; (void)n_in; (void)d_ws; (void)ws_size; (void)out_size;
    const float* x = (const float*)d_in[0];
    const float* y = (const float*)d_in[1];
    float* out = (float*)d_out;

    constexpr size_t LDSB = 4 * NPTS * DIM * sizeof(__bf16)
                          + 3 * NPTS * sizeof(float);      // 140 KiB
    hipFuncSetAttribute((const void*)sinkhorn_kernel,
                        hipFuncAttributeMaxDynamicSharedMemorySize, (int)LDSB);

    hipMemsetAsync(out, 0, sizeof(float), stream);
    hipLaunchKernelGGL(sinkhorn_kernel, dim3(GRAPHS * 3), dim3(THREADS), LDSB,
                       stream, x, y, out);
}

// Round 9
// 2099.678 us; speedup vs baseline: 1.0499x; 1.0499x over previous
//
#include <hip/hip_runtime.h>

#define NPTS    1024
#define DIM     16
#define GRAPHS  64
#define NITERS  20
#define THREADS 1024
#define NWAVES  (THREADS / 64)
#define RT      4        // 16-row tiles per wave (16 waves x 64 rows)
#define NCHUNK  16       // 64 j-tiles, 4 per chunk
#define WIN     100.0f   // prune window (log2 units) after warm-up
#define NWARM   4        // iterations with pruning disabled (exact trajectory)

typedef __bf16 bf16x8 __attribute__((ext_vector_type(8)));
typedef __bf16 bf16x4 __attribute__((ext_vector_type(4)));
typedef float  f32x4  __attribute__((ext_vector_type(4)));

#define KLOG 577.07801635558536f      // log2(e)/eps, eps = 0.05^2
#define CLSE 0.0017328679513998633f   // eps*ln2   (KLOG*CLSE == 1)

static __device__ __forceinline__ float fexp2(float x){ return __builtin_amdgcn_exp2f(x); }
static __device__ __forceinline__ float flog2(float x){ return __builtin_amdgcn_logf(x); }

// global f32 cloud -> LDS split-bf16 (hi, lo), optionally pre-scaled
static __device__ __forceinline__ void split_store(
    __bf16* __restrict__ dh, __bf16* __restrict__ dl,
    const float* __restrict__ src, const float scale, const int tid)
{
    const float4* s4 = (const float4*)src;
    #pragma unroll 1
    for (int k = 0; k < (NPTS * DIM / 4) / THREADS; ++k) {
        const int idx = tid + k * THREADS;
        const float4 v = s4[idx];
        const float f0 = v.x * scale, f1 = v.y * scale,
                    f2 = v.z * scale, f3 = v.w * scale;
        bf16x4 h, l;
        h[0] = (__bf16)f0; l[0] = (__bf16)(f0 - (float)h[0]);
        h[1] = (__bf16)f1; l[1] = (__bf16)(f1 - (float)h[1]);
        h[2] = (__bf16)f2; l[2] = (__bf16)(f2 - (float)h[2]);
        h[3] = (__bf16)f3; l[3] = (__bf16)(f3 - (float)h[3]);
        *(bf16x4*)(dh + idx * 4) = h;
        *(bf16x4*)(dl + idx * 4) = l;
    }
}

// One half-iteration, single fused sweep with carried per-row baselines.
// MFMA C-init carries ONLY t_j (loop-invariant per tile) so the MFMA stream
// pipelines; the baseline mr enters in the VALU consumer (re = acc - mr).
// Rare wave-uniform fixup raises mr when re exceeds it; per-tile prune
// skips exp2 work when all re < -win.
static __device__ __forceinline__ float sink_pass(
    const __bf16* __restrict__ rH, const __bf16* __restrict__ rL,
    const __bf16* __restrict__ cH, const __bf16* __restrict__ cL,
    float* __restrict__ sB, float* __restrict__ sM,
    const int wbase, const int lane, const float win)
{
    const int g  = lane >> 4;
    const int n  = lane & 15;
    const int gh = g & 1;

    // A fragments: [row-hi | row-lo] along K=32 (rows pre-scaled by KLOG)
    bf16x8 A[RT];
    {
        const __bf16* ap = (g < 2 ? rH : rL) + (wbase + n) * DIM + gh * 8;
        #pragma unroll
        for (int rt = 0; rt < RT; ++rt)
            A[rt] = *(const bf16x8*)(ap + rt * (16 * DIM));
    }

    // baselines (identical across the 16 column-lanes of each g-group)
    float mr[RT][4], s[RT][4];
    #pragma unroll
    for (int rt = 0; rt < RT; ++rt) {
        const f32x4 v = *(const f32x4*)(sM + wbase + rt * 16 + g * 4);
        #pragma unroll
        for (int e = 0; e < 4; ++e) { mr[rt][e] = v[e]; s[rt][e] = 0.0f; }
    }

    const __bf16* b1p = cH + n * DIM + gh * 8;   // [yh | yh]
    const __bf16* b2p = cL + n * DIM + gh * 8;   // [yl | yl]
    const float*  tp  = sB + n;

    #pragma unroll 1
    for (int c = 0; c < NCHUNK; ++c) {
        float t[4];
        #pragma unroll
        for (int q = 0; q < 4; ++q) t[q] = tp[c * 64 + q * 16];
        const int off = c * (4 * 16 * DIM);
        #pragma unroll
        for (int qq = 0; qq < 2; ++qq) {
            bf16x8 B1[2], B2[2];
            B1[0] = *(const bf16x8*)(b1p + off + (qq * 2 + 0) * (16 * DIM));
            B1[1] = *(const bf16x8*)(b1p + off + (qq * 2 + 1) * (16 * DIM));
            B2[0] = *(const bf16x8*)(b2p + off + (qq * 2 + 0) * (16 * DIM));
            B2[1] = *(const bf16x8*)(b2p + off + (qq * 2 + 1) * (16 * DIM));
            #pragma unroll
            for (int rt = 0; rt < RT; ++rt) {
                #pragma unroll
                for (int p = 0; p < 2; ++p) {
                    const float tq = t[qq * 2 + p];
                    f32x4 acc = { tq, tq, tq, tq };      // loop-invariant C-init
                    acc = __builtin_amdgcn_mfma_f32_16x16x32_bf16(A[rt], B2[p], acc, 0, 0, 0);
                    acc = __builtin_amdgcn_mfma_f32_16x16x32_bf16(A[rt], B1[p], acc, 0, 0, 0);
                    // VALU consumer: relative scores vs carried baseline
                    float re0 = acc[0] - mr[rt][0];
                    float re1 = acc[1] - mr[rt][1];
                    float re2 = acc[2] - mr[rt][2];
                    float re3 = acc[3] - mr[rt][3];
                    const float h = fmaxf(fmaxf(re0, re1), fmaxf(re2, re3));
                    if (__any(h > 1.0f)) {
                        // rare: baseline exceeded -> raise mr wave-uniformly
                        float re[4] = { re0, re1, re2, re3 };
                        #pragma unroll
                        for (int e = 0; e < 4; ++e) {
                            float cm = re[e];
                            cm = fmaxf(cm, __shfl_xor(cm, 1, 64));
                            cm = fmaxf(cm, __shfl_xor(cm, 2, 64));
                            cm = fmaxf(cm, __shfl_xor(cm, 4, 64));
                            cm = fmaxf(cm, __shfl_xor(cm, 8, 64));
                            const float sh = fmaxf(cm, 0.0f);
                            s[rt][e] = fmaf(s[rt][e], fexp2(-sh),
                                            fexp2(re[e] - sh));
                            mr[rt][e] += sh;
                        }
                    } else if (__any(h > -win)) {
                        s[rt][0] += fexp2(re0);
                        s[rt][1] += fexp2(re1);
                        s[rt][2] += fexp2(re2);
                        s[rt][3] += fexp2(re3);
                    }
                }
            }
        }
    }

    // merge sums across the 16 column-class lanes (baselines identical)
    float lsum = 0.0f;
    float lse[RT][4];
    #pragma unroll
    for (int rt = 0; rt < RT; ++rt) {
        #pragma unroll
        for (int e = 0; e < 4; ++e) {
            float ss = s[rt][e];
            ss += __shfl_xor(ss, 1, 64);
            ss += __shfl_xor(ss, 2, 64);
            ss += __shfl_xor(ss, 4, 64);
            ss += __shfl_xor(ss, 8, 64);
            ss = fmaxf(ss, 1.0e-30f);        // no -inf propagation
            const float l = mr[rt][e] + flog2(ss);
            lsum += l;
            lse[rt][e] = l;
        }
    }

    __syncthreads();     // all reads of sB/sM complete block-wide
    if (n == 0) {
        #pragma unroll
        for (int rt = 0; rt < RT; ++rt) {
            const int row4 = wbase + rt * 16 + g * 4;
            f32x4 mv = { -10.0f - lse[rt][0], -10.0f - lse[rt][1],
                         -10.0f - lse[rt][2], -10.0f - lse[rt][3] };
            f32x4 lv = { lse[rt][0], lse[rt][1], lse[rt][2], lse[rt][3] };
            *(f32x4*)(sB + row4) = mv;
            *(f32x4*)(sM + row4) = lv;
        }
    }
    __syncthreads();
    return lsum;
}

__global__ __launch_bounds__(THREADS)
void sinkhorn_kernel(const float* __restrict__ xg,
                     const float* __restrict__ yg,
                     float* __restrict__ out)
{
    extern __shared__ char ldsraw[];
    __bf16* sxh = (__bf16*)ldsraw;              // [1024][16] hi of K*x
    __bf16* sxl = sxh + NPTS * DIM;             // lo of K*x
    __bf16* syh = sxl + NPTS * DIM;             // hi of y
    __bf16* syl = syh + NPTS * DIM;             // lo of y
    float*  sB  = (float*)(syl + NPTS * DIM);   // [1024] messages (log2 units)
    float*  sMf = sB + NPTS;                    // [1024] carried lse, f-rows
    float*  sMg = sMf + NPTS;                   // [1024] carried lse, g-rows

    const int tid   = threadIdx.x;
    const int lane  = tid & 63;
    const int wave  = tid >> 6;
    const int wbase = wave * (RT * 16);

    const int graph = blockIdx.x / 3;
    const int term  = blockIdx.x - graph * 3;   // 0:(x,y) 1:(x,x) 2:(y,y)
    const float* xb = xg + (size_t)graph * (NPTS * DIM);
    const float* yb = yg + (size_t)graph * (NPTS * DIM);
    const float* Xp = (term == 2) ? yb : xb;
    const float* Yp = (term == 1) ? xb : yb;

    split_store(sxh, sxl, Xp, KLOG, tid);       // row side carries the 1/eps scale
    split_store(syh, syl, Yp, 1.0f, tid);

    // prologue (thread = row): quadratic terms, message init, baseline seeds
    float csum;
    {
        const float4* xr = (const float4*)(Xp + tid * DIM);
        const float4* yr = (const float4*)(Yp + tid * DIM);
        float hx = 0.0f, hy = 0.0f, d = 0.0f;
        #pragma unroll
        for (int c = 0; c < 4; ++c) {
            const float4 a = xr[c], b = yr[c];
            hx = fmaf(a.x, a.x, hx); hx = fmaf(a.y, a.y, hx);
            hx = fmaf(a.z, a.z, hx); hx = fmaf(a.w, a.w, hx);
            hy = fmaf(b.x, b.x, hy); hy = fmaf(b.y, b.y, hy);
            hy = fmaf(b.z, b.z, hy); hy = fmaf(b.w, b.w, hy);
            d  = fmaf(a.x, b.x, d);  d  = fmaf(a.y, b.y, d);
            d  = fmaf(a.z, b.z, d);  d  = fmaf(a.w, b.w, d);
        }
        hx *= 0.5f; hy *= 0.5f;
        csum = hx + hy;
        sB[tid]  = fmaf(-KLOG, hy, -10.0f);          // t_j for g = 0
        sMf[tid] = fmaf(KLOG, d - hy, -10.0f);       // underestimate of f-pass-0 max
        sMg[tid] = fmaf(KLOG, d - hx, -10.0f);       // underestimate of g-pass-0 max
    }
    __syncthreads();

    float fsum = 0.0f, gsum = 0.0f;
    #pragma unroll 1
    for (int it = 0; it < NITERS; ++it) {
        const float w = (it < NWARM) ? 1.0e30f : WIN;   // warm: exact (no prune)
        fsum = sink_pass(sxh, sxl, syh, syl, sB, sMf, wbase, lane, w);  // f
        gsum = sink_pass(syh, syl, sxh, sxl, sB, sMg, wbase, lane, w);  // g
    }
    fsum = sink_pass(sxh, sxl, syh, syl, sB, sMf, wbase, lane, WIN);    // final f

    // OT = [csum - CLSE*(sum lse_f + sum lse_g)] / NPTS  (lse sums x16 dup)
    float v = fmaf(-CLSE, (fsum + gsum) * (1.0f / 16.0f), csum);
    #pragma unroll
    for (int off = 32; off; off >>= 1) v += __shfl_down(v, off, 64);
    if (lane == 0) sB[wave] = v;
    __syncthreads();
    if (tid == 0) {
        float tot = 0.0f;
        #pragma unroll
        for (int w = 0; w < NWAVES; ++w) tot += sB[w];
        const float wgt = ((term == 0) ? 1.0f : -0.5f)
                          / ((float)GRAPHS * (float)NPTS);
        atomicAdd(out, wgt * tot);
    }
}

extern "C" void kernel_launch(void* const* d_in, const int* in_sizes, int n_in,
                              void* d_out, int out_size, void* d_ws, size_t ws_size,
                              hipStream_t stream)
{
    (void)in_sizes; (void)n_in; (void)d_ws; (void)ws_size; (void)out_size;
    const float* x = (const float*)d_in[0];
    const float* y = (const float*)d_in[1];
    float* out = (float*)d_out;

    constexpr size_t LDSB = 4 * NPTS * DIM * sizeof(__bf16)
                          + 3 * NPTS * sizeof(float);      // 140 KiB
    hipFuncSetAttribute((const void*)sinkhorn_kernel,
                        hipFuncAttributeMaxDynamicSharedMemorySize, (int)LDSB);

    hipMemsetAsync(out, 0, sizeof(float), stream);
    hipLaunchKernelGGL(sinkhorn_kernel, dim3(GRAPHS * 3), dim3(THREADS), LDSB,
                       stream, x, y, out);
}

// Round 10
// 1862.714 us; speedup vs baseline: 1.1834x; 1.1272x over previous
//
#include <hip/hip_runtime.h>

#define NPTS    1024
#define DIM     16
#define GRAPHS  64
#define NITERS  20
#define THREADS 1024
#define NWAVES  (THREADS / 64)
#define RT      4        // 16-row tiles per wave (16 waves x 64 rows)
#define NCHUNK  16       // 64 j-tiles, 4 per chunk
#define WIN     80.0f    // prune window (log2 units)

typedef __bf16 bf16x8 __attribute__((ext_vector_type(8)));
typedef __bf16 bf16x4 __attribute__((ext_vector_type(4)));
typedef float  f32x4  __attribute__((ext_vector_type(4)));

#define KLOG 577.07801635558536f      // log2(e)/eps, eps = 0.05^2
#define CLSE 0.0017328679513998633f   // eps*ln2   (KLOG*CLSE == 1)

static __device__ __forceinline__ float fexp2(float x){ return __builtin_amdgcn_exp2f(x); }
static __device__ __forceinline__ float flog2(float x){ return __builtin_amdgcn_logf(x); }

static __device__ __forceinline__ float halfsq16(const float* p)
{
    const float4* v = (const float4*)p;
    float a = 0.0f;
    #pragma unroll
    for (int c = 0; c < 4; ++c) {
        const float4 q = v[c];
        a = fmaf(q.x, q.x, a); a = fmaf(q.y, q.y, a);
        a = fmaf(q.z, q.z, a); a = fmaf(q.w, q.w, a);
    }
    return 0.5f * a;
}

// global f32 cloud -> LDS split-bf16 (hi, lo), optionally pre-scaled
static __device__ __forceinline__ void split_store(
    __bf16* __restrict__ dh, __bf16* __restrict__ dl,
    const float* __restrict__ src, const float scale, const int tid)
{
    const float4* s4 = (const float4*)src;
    #pragma unroll 1
    for (int k = 0; k < (NPTS * DIM / 4) / THREADS; ++k) {
        const int idx = tid + k * THREADS;
        const float4 v = s4[idx];
        const float f0 = v.x * scale, f1 = v.y * scale,
                    f2 = v.z * scale, f3 = v.w * scale;
        bf16x4 h, l;
        h[0] = (__bf16)f0; l[0] = (__bf16)(f0 - (float)h[0]);
        h[1] = (__bf16)f1; l[1] = (__bf16)(f1 - (float)h[1]);
        h[2] = (__bf16)f2; l[2] = (__bf16)(f2 - (float)h[2]);
        h[3] = (__bf16)f3; l[3] = (__bf16)(f3 - (float)h[3]);
        *(bf16x4*)(dh + idx * 4) = h;
        *(bf16x4*)(dl + idx * 4) = l;
    }
}

// One half-iteration, two-phase (round-7 algorithm), software-pipelined:
//  pass 1: m[row] = max_j (t_j + approx dot)  (B = hi only, no trans)
//  pass 2: s[row] = sum_j 2^{t_j + dot - m}, quadrant-pruned at -WIN
// In both passes, tile k+1's MFMA is issued BEFORE tile k's consumer so the
// consumer runs in the MFMA-latency shadow (2-state rotation, static idx).
static __device__ __forceinline__ float sink_pass(
    const __bf16* __restrict__ rH, const __bf16* __restrict__ rL,
    const __bf16* __restrict__ cH, const __bf16* __restrict__ cL,
    float* __restrict__ sB, const int wbase, const int lane)
{
    const int g  = lane >> 4;
    const int n  = lane & 15;
    const int gh = g & 1;

    // A fragments: [row-hi | row-lo] along K=32 (rows pre-scaled by KLOG)
    bf16x8 A[RT];
    {
        const __bf16* ap = (g < 2 ? rH : rL) + (wbase + n) * DIM + gh * 8;
        #pragma unroll
        for (int rt = 0; rt < RT; ++rt)
            A[rt] = *(const bf16x8*)(ap + rt * (16 * DIM));
    }

    const __bf16* b1p = cH + n * DIM + gh * 8;   // [yh | yh]
    const __bf16* b2p = cL + n * DIM + gh * 8;   // [yl | yl]
    const float*  tp  = sB + n;

    // ---------------- pass 1: row maxima (approx, trans-free) ----------------
    float m[RT][4];
    #pragma unroll
    for (int rt = 0; rt < RT; ++rt) {
        #pragma unroll
        for (int e = 0; e < 4; ++e) m[rt][e] = -3.0e38f;
    }

    #pragma unroll 1
    for (int c = 0; c < NCHUNK; ++c) {
        const int off = c * (4 * 16 * DIM);
        float t[4]; bf16x8 B[4];
        #pragma unroll
        for (int q = 0; q < 4; ++q) {
            t[q] = tp[c * 64 + q * 16];
            B[q] = *(const bf16x8*)(b1p + off + q * (16 * DIM));
        }
        // 16 tiles: k = q*4 + rt; rotate producer one tile ahead
        f32x4 w[2];
        {
            f32x4 a0 = { t[0], t[0], t[0], t[0] };
            w[0] = __builtin_amdgcn_mfma_f32_16x16x32_bf16(A[0], B[0], a0, 0, 0, 0);
        }
        #pragma unroll
        for (int k = 0; k < 16; ++k) {
            if (k < 15) {
                const int kn = k + 1, qn = kn >> 2, rn = kn & 3;
                f32x4 a = { t[qn], t[qn], t[qn], t[qn] };
                w[kn & 1] = __builtin_amdgcn_mfma_f32_16x16x32_bf16(A[rn], B[qn], a, 0, 0, 0);
            }
            const f32x4 wc = w[k & 1];
            const int rt = k & 3;
            m[rt][0] = fmaxf(m[rt][0], wc[0]);
            m[rt][1] = fmaxf(m[rt][1], wc[1]);
            m[rt][2] = fmaxf(m[rt][2], wc[2]);
            m[rt][3] = fmaxf(m[rt][3], wc[3]);
        }
    }

    // merge maxima across the 16 column-class lanes
    #pragma unroll
    for (int rt = 0; rt < RT; ++rt) {
        #pragma unroll
        for (int e = 0; e < 4; ++e) {
            float mm = m[rt][e];
            #pragma unroll
            for (int d = 1; d < 16; d <<= 1)
                mm = fmaxf(mm, __shfl_xor(mm, d, 64));
            m[rt][e] = mm;
        }
    }

    // ---------------- pass 2: pruned exp-sums (shared m) ----------------
    float s[RT][4];
    #pragma unroll
    for (int rt = 0; rt < RT; ++rt) {
        #pragma unroll
        for (int e = 0; e < 4; ++e) s[rt][e] = 0.0f;
    }

    #pragma unroll 1
    for (int c = 0; c < NCHUNK; ++c) {
        const int off = c * (4 * 16 * DIM);
        float t[4]; bf16x8 B1[4], B2[4];
        #pragma unroll
        for (int q = 0; q < 4; ++q) {
            t[q]  = tp[c * 64 + q * 16];
            B1[q] = *(const bf16x8*)(b1p + off + q * (16 * DIM));
            B2[q] = *(const bf16x8*)(b2p + off + q * (16 * DIM));
        }
        f32x4 w[2];
        {
            f32x4 a0 = { t[0] - m[0][0], t[0] - m[0][1],
                         t[0] - m[0][2], t[0] - m[0][3] };
            a0 = __builtin_amdgcn_mfma_f32_16x16x32_bf16(A[0], B2[0], a0, 0, 0, 0);
            w[0] = __builtin_amdgcn_mfma_f32_16x16x32_bf16(A[0], B1[0], a0, 0, 0, 0);
        }
        #pragma unroll
        for (int k = 0; k < 16; ++k) {
            if (k < 15) {
                const int kn = k + 1, qn = kn >> 2, rn = kn & 3;
                f32x4 a = { t[qn] - m[rn][0], t[qn] - m[rn][1],
                            t[qn] - m[rn][2], t[qn] - m[rn][3] };
                a = __builtin_amdgcn_mfma_f32_16x16x32_bf16(A[rn], B2[qn], a, 0, 0, 0);
                w[kn & 1] = __builtin_amdgcn_mfma_f32_16x16x32_bf16(A[rn], B1[qn], a, 0, 0, 0);
            }
            const f32x4 wc = w[k & 1];
            const int rt = k & 3;
            const float h = fmaxf(fmaxf(wc[0], wc[1]), fmaxf(wc[2], wc[3]));
            if (__any(h > -WIN)) {          // quadrant carries visible mass
                s[rt][0] += fexp2(wc[0]);
                s[rt][1] += fexp2(wc[1]);
                s[rt][2] += fexp2(wc[2]);
                s[rt][3] += fexp2(wc[3]);
            }
        }
    }

    // merge sums across the 16 column-class lanes (m already shared)
    float lsum = 0.0f;
    float msg[RT][4];
    #pragma unroll
    for (int rt = 0; rt < RT; ++rt) {
        #pragma unroll
        for (int e = 0; e < 4; ++e) {
            float ss = s[rt][e];
            #pragma unroll
            for (int d = 1; d < 16; d <<= 1)
                ss += __shfl_xor(ss, d, 64);
            const float l = m[rt][e] + flog2(ss);
            lsum += l;
            msg[rt][e] = -10.0f - l;
        }
    }

    __syncthreads();     // all reads of sB complete block-wide
    if (n == 0) {
        #pragma unroll
        for (int rt = 0; rt < RT; ++rt) {
            f32x4 v = { msg[rt][0], msg[rt][1], msg[rt][2], msg[rt][3] };
            *(f32x4*)(sB + wbase + rt * 16 + g * 4) = v;
        }
    }
    __syncthreads();
    return lsum;
}

__global__ __launch_bounds__(THREADS)
void sinkhorn_kernel(const float* __restrict__ xg,
                     const float* __restrict__ yg,
                     float* __restrict__ out)
{
    extern __shared__ char ldsraw[];
    __bf16* sxh = (__bf16*)ldsraw;              // [1024][16] hi of K*x
    __bf16* sxl = sxh + NPTS * DIM;             // lo of K*x
    __bf16* syh = sxl + NPTS * DIM;             // hi of y
    __bf16* syl = syh + NPTS * DIM;             // lo of y
    float*  sB  = (float*)(syl + NPTS * DIM);   // [1024] messages (log2 units)

    const int tid   = threadIdx.x;
    const int lane  = tid & 63;
    const int wave  = tid >> 6;
    const int wbase = wave * (RT * 16);

    const int graph = blockIdx.x / 3;
    const int term  = blockIdx.x - graph * 3;   // 0:(x,y) 1:(x,x) 2:(y,y)
    const float* xb = xg + (size_t)graph * (NPTS * DIM);
    const float* yb = yg + (size_t)graph * (NPTS * DIM);
    const float* Xp = (term == 2) ? yb : xb;
    const float* Yp = (term == 1) ? xb : yb;

    split_store(sxh, sxl, Xp, KLOG, tid);       // row side carries the 1/eps scale
    split_store(syh, syl, Yp, 1.0f, tid);

    // quadratic terms (exact f32) + message init (thread = row)
    float csum;
    {
        const float hx = halfsq16(Xp + tid * DIM);
        const float hy = halfsq16(Yp + tid * DIM);
        csum = hx + hy;
        sB[tid] = fmaf(-KLOG, hy, -10.0f);      // t_j for g = 0
    }
    __syncthreads();

    float fsum = 0.0f, gsum = 0.0f;
    #pragma unroll 1
    for (int it = 0; it < NITERS; ++it) {
        fsum = sink_pass(sxh, sxl, syh, syl, sB, wbase, lane);   // f-update
        gsum = sink_pass(syh, syl, sxh, sxl, sB, wbase, lane);   // g-update
    }
    fsum = sink_pass(sxh, sxl, syh, syl, sB, wbase, lane);       // final f

    // OT = [csum - CLSE*(sum lse_f + sum lse_g)] / NPTS  (lse sums x16 dup)
    float v = fmaf(-CLSE, (fsum + gsum) * (1.0f / 16.0f), csum);
    #pragma unroll
    for (int off = 32; off; off >>= 1) v += __shfl_down(v, off, 64);
    if (lane == 0) sB[wave] = v;
    __syncthreads();
    if (tid == 0) {
        float tot = 0.0f;
        #pragma unroll
        for (int w = 0; w < NWAVES; ++w) tot += sB[w];
        const float wgt = ((term == 0) ? 1.0f : -0.5f)
                          / ((float)GRAPHS * (float)NPTS);
        atomicAdd(out, wgt * tot);
    }
}

extern "C" void kernel_launch(void* const* d_in, const int* in_sizes, int n_in,
                              void* d_out, int out_size, void* d_ws, size_t ws_size,
                              hipStream_t stream)
{
    (void)in_sizes; (void)n_in; (void)d_ws; (void)ws_size; (void)out_size;
    const float* x = (const float*)d_in[0];
    const float* y = (const float*)d_in[1];
    float* out = (float*)d_out;

    constexpr size_t LDSB = 4 * NPTS * DIM * sizeof(__bf16)
                          + NPTS * sizeof(float);          // 132 KiB
    hipFuncSetAttribute((const void*)sinkhorn_kernel,
                        hipFuncAttributeMaxDynamicSharedMemorySize, (int)LDSB);

    hipMemsetAsync(out, 0, sizeof(float), stream);
    hipLaunchKernelGGL(sinkhorn_kernel, dim3(GRAPHS * 3), dim3(THREADS), LDSB,
                       stream, x, y, out);
}

// Round 11
// 1578.428 us; speedup vs baseline: 1.3966x; 1.1801x over previous
//
#include <hip/hip_runtime.h>

#define NPTS    1024
#define DIM     16
#define GRAPHS  64
#define NITERS  20
#define THREADS 1024
#define NWAVES  (THREADS / 64)
#define RT      4        // 16-row tiles per wave (16 waves x 64 rows)
#define NCHUNK  16       // 64 j-tiles, 4 per chunk
#define WINW    80.0f    // prune window, warm two-phase passes (round-7 proven)
#define WINB    45.0f    // base prune window, fused passes
#define NWARM   3        // exact two-phase iterations before fused passes

typedef __bf16 bf16x8 __attribute__((ext_vector_type(8)));
typedef float  f32x4  __attribute__((ext_vector_type(4)));

#define KLOG 577.07801635558536f      // log2(e)/eps, eps = 0.05^2
#define CLSE 0.0017328679513998633f   // eps*ln2   (KLOG*CLSE == 1)

static __device__ __forceinline__ float fexp2(float x){ return __builtin_amdgcn_exp2f(x); }
static __device__ __forceinline__ float flog2(float x){ return __builtin_amdgcn_logf(x); }

static __device__ __forceinline__ float halfsq16(const float* p)
{
    const float4* v = (const float4*)p;
    float a = 0.0f;
    #pragma unroll
    for (int c = 0; c < 4; ++c) {
        const float4 q = v[c];
        a = fmaf(q.x, q.x, a); a = fmaf(q.y, q.y, a);
        a = fmaf(q.z, q.z, a); a = fmaf(q.w, q.w, a);
    }
    return 0.5f * a;
}

// global f32 cloud -> LDS split-bf16 (hi, lo), optionally pre-scaled
static __device__ __forceinline__ void split_store(
    __bf16* __restrict__ dh, __bf16* __restrict__ dl,
    const float* __restrict__ src, const float scale, const int tid)
{
    const float4* s4 = (const float4*)src;
    #pragma unroll 1
    for (int k = 0; k < (NPTS * DIM / 4) / THREADS; ++k) {
        const int idx = tid + k * THREADS;
        const float4 v = s4[idx];
        const float f0 = v.x * scale, f1 = v.y * scale,
                    f2 = v.z * scale, f3 = v.w * scale;
        __bf16 h0 = (__bf16)f0, h1 = (__bf16)f1,
               h2 = (__bf16)f2, h3 = (__bf16)f3;
        bf16x8 dummy;
        (void)dummy;
        struct { __bf16 a,b,c,d; } H = { h0,h1,h2,h3 },
              L = { (__bf16)(f0-(float)h0), (__bf16)(f1-(float)h1),
                    (__bf16)(f2-(float)h2), (__bf16)(f3-(float)h3) };
        *(decltype(H)*)(dh + idx*4) = H;
        *(decltype(L)*)(dl + idx*4) = L;
    }
}

// Shared epilogue: barrier, write messages/lse, track message drift, barrier.
static __device__ __forceinline__ void write_msgs(
    const float (*lse)[4], float* __restrict__ sBw, float* __restrict__ sMw,
    float* __restrict__ sDmax, float* __restrict__ sDmin,
    const int wbase, const int lane)
{
    const int g = lane >> 4;
    const int n = lane & 15;
    __syncthreads();     // all reads of sBr/sMr/sD complete block-wide
    if (n == 0) {
        float dmx = -3.0e38f, dmn = 3.0e38f;
        #pragma unroll
        for (int rt = 0; rt < RT; ++rt) {
            const int row4 = wbase + rt * 16 + g * 4;
            const f32x4 old = *(const f32x4*)(sBw + row4);
            f32x4 mv, lv;
            #pragma unroll
            for (int e = 0; e < 4; ++e) {
                lv[e] = lse[rt][e];
                mv[e] = -10.0f - lse[rt][e];
                const float d = mv[e] - old[e];
                dmx = fmaxf(dmx, d); dmn = fminf(dmn, d);
            }
            *(f32x4*)(sBw + row4) = mv;
            *(f32x4*)(sMw + row4) = lv;
        }
        sDmax[(wbase >> 4) + g] = dmx;
        sDmin[(wbase >> 4) + g] = dmn;
    }
    __syncthreads();
}

// Warm half-iteration: exact two-phase (round-10 structure), plus lse/drift
// bookkeeping for the fused passes that follow.
static __device__ __forceinline__ float warm_pass(
    const __bf16* __restrict__ rH, const __bf16* __restrict__ rL,
    const __bf16* __restrict__ cH, const __bf16* __restrict__ cL,
    const float* __restrict__ sBr, float* __restrict__ sBw,
    float* __restrict__ sMw, float* __restrict__ sDmax, float* __restrict__ sDmin,
    const int wbase, const int lane)
{
    const int g  = lane >> 4;
    const int n  = lane & 15;
    const int gh = g & 1;

    bf16x8 A[RT];
    {
        const __bf16* ap = (g < 2 ? rH : rL) + (wbase + n) * DIM + gh * 8;
        #pragma unroll
        for (int rt = 0; rt < RT; ++rt)
            A[rt] = *(const bf16x8*)(ap + rt * (16 * DIM));
    }
    const __bf16* b1p = cH + n * DIM + gh * 8;
    const __bf16* b2p = cL + n * DIM + gh * 8;
    const float*  tp  = sBr + n;

    // pass 1: approx row maxima (B = hi only)
    float m[RT][4];
    #pragma unroll
    for (int rt = 0; rt < RT; ++rt)
        #pragma unroll
        for (int e = 0; e < 4; ++e) m[rt][e] = -3.0e38f;

    #pragma unroll 1
    for (int c = 0; c < NCHUNK; ++c) {
        const int off = c * (4 * 16 * DIM);
        float t[4]; bf16x8 B[4];
        #pragma unroll
        for (int q = 0; q < 4; ++q) {
            t[q] = tp[c * 64 + q * 16];
            B[q] = *(const bf16x8*)(b1p + off + q * (16 * DIM));
        }
        f32x4 w[2];
        {
            f32x4 a0 = { t[0], t[0], t[0], t[0] };
            w[0] = __builtin_amdgcn_mfma_f32_16x16x32_bf16(A[0], B[0], a0, 0, 0, 0);
        }
        #pragma unroll
        for (int k = 0; k < 16; ++k) {
            if (k < 15) {
                const int kn = k + 1, qn = kn >> 2, rn = kn & 3;
                f32x4 a = { t[qn], t[qn], t[qn], t[qn] };
                w[kn & 1] = __builtin_amdgcn_mfma_f32_16x16x32_bf16(A[rn], B[qn], a, 0, 0, 0);
            }
            const f32x4 wc = w[k & 1];
            const int rt = k & 3;
            m[rt][0] = fmaxf(m[rt][0], wc[0]);
            m[rt][1] = fmaxf(m[rt][1], wc[1]);
            m[rt][2] = fmaxf(m[rt][2], wc[2]);
            m[rt][3] = fmaxf(m[rt][3], wc[3]);
        }
    }
    #pragma unroll
    for (int rt = 0; rt < RT; ++rt)
        #pragma unroll
        for (int e = 0; e < 4; ++e) {
            float mm = m[rt][e];
            #pragma unroll
            for (int d = 1; d < 16; d <<= 1)
                mm = fmaxf(mm, __shfl_xor(mm, d, 64));
            m[rt][e] = mm;
        }

    // pass 2: pruned exp-sums
    float s[RT][4];
    #pragma unroll
    for (int rt = 0; rt < RT; ++rt)
        #pragma unroll
        for (int e = 0; e < 4; ++e) s[rt][e] = 0.0f;

    #pragma unroll 1
    for (int c = 0; c < NCHUNK; ++c) {
        const int off = c * (4 * 16 * DIM);
        float t[4]; bf16x8 B1[4], B2[4];
        #pragma unroll
        for (int q = 0; q < 4; ++q) {
            t[q]  = tp[c * 64 + q * 16];
            B1[q] = *(const bf16x8*)(b1p + off + q * (16 * DIM));
            B2[q] = *(const bf16x8*)(b2p + off + q * (16 * DIM));
        }
        f32x4 w[2];
        {
            f32x4 a0 = { t[0] - m[0][0], t[0] - m[0][1],
                         t[0] - m[0][2], t[0] - m[0][3] };
            a0 = __builtin_amdgcn_mfma_f32_16x16x32_bf16(A[0], B2[0], a0, 0, 0, 0);
            w[0] = __builtin_amdgcn_mfma_f32_16x16x32_bf16(A[0], B1[0], a0, 0, 0, 0);
        }
        #pragma unroll
        for (int k = 0; k < 16; ++k) {
            if (k < 15) {
                const int kn = k + 1, qn = kn >> 2, rn = kn & 3;
                f32x4 a = { t[qn] - m[rn][0], t[qn] - m[rn][1],
                            t[qn] - m[rn][2], t[qn] - m[rn][3] };
                a = __builtin_amdgcn_mfma_f32_16x16x32_bf16(A[rn], B2[qn], a, 0, 0, 0);
                w[kn & 1] = __builtin_amdgcn_mfma_f32_16x16x32_bf16(A[rn], B1[qn], a, 0, 0, 0);
            }
            const f32x4 wc = w[k & 1];
            const int rt = k & 3;
            const float h = fmaxf(fmaxf(wc[0], wc[1]), fmaxf(wc[2], wc[3]));
            if (__any(h > -WINW)) {
                s[rt][0] += fexp2(wc[0]);
                s[rt][1] += fexp2(wc[1]);
                s[rt][2] += fexp2(wc[2]);
                s[rt][3] += fexp2(wc[3]);
            }
        }
    }

    float lsum = 0.0f;
    float lse[RT][4];
    #pragma unroll
    for (int rt = 0; rt < RT; ++rt)
        #pragma unroll
        for (int e = 0; e < 4; ++e) {
            float ss = s[rt][e];
            #pragma unroll
            for (int d = 1; d < 16; d <<= 1)
                ss += __shfl_xor(ss, d, 64);
            ss = fmaxf(ss, 1.0e-30f);
            const float l = m[rt][e] + flog2(ss);
            lsum += l;
            lse[rt][e] = l;
        }

    write_msgs(lse, sBw, sMw, sDmax, sDmin, wbase, lane);
    return lsum;
}

// Fused half-iteration: single sweep; m_est = lse_prev + maxDrift is a
// guaranteed (inductive) upper bound on the true row max -> exp2 args <= 0,
// no fixup. Prune window widens by the drift spread, so early/turbulent
// passes degrade to take-all (exact) automatically.
static __device__ __forceinline__ float fused_pass(
    const __bf16* __restrict__ rH, const __bf16* __restrict__ rL,
    const __bf16* __restrict__ cH, const __bf16* __restrict__ cL,
    const float* __restrict__ sBr, float* __restrict__ sBw,
    float* __restrict__ sM, float* __restrict__ sDmax, float* __restrict__ sDmin,
    const int wbase, const int lane)
{
    const int g  = lane >> 4;
    const int n  = lane & 15;
    const int gh = g & 1;

    bf16x8 A[RT];
    {
        const __bf16* ap = (g < 2 ? rH : rL) + (wbase + n) * DIM + gh * 8;
        #pragma unroll
        for (int rt = 0; rt < RT; ++rt)
            A[rt] = *(const bf16x8*)(ap + rt * (16 * DIM));
    }

    // column-message drift of the preceding pass (64 partials -> scalar)
    float dmx = sDmax[lane], dmn = sDmin[lane];
    #pragma unroll
    for (int d = 1; d < 64; d <<= 1) {
        dmx = fmaxf(dmx, __shfl_xor(dmx, d, 64));
        dmn = fminf(dmn, __shfl_xor(dmn, d, 64));
    }
    const float win = WINB + fmaxf(0.0f, dmx - dmn);

    float me[RT][4], s[RT][4];
    #pragma unroll
    for (int rt = 0; rt < RT; ++rt) {
        const f32x4 v = *(const f32x4*)(sM + wbase + rt * 16 + g * 4);
        #pragma unroll
        for (int e = 0; e < 4; ++e) { me[rt][e] = v[e] + dmx; s[rt][e] = 0.0f; }
    }

    const __bf16* b1p = cH + n * DIM + gh * 8;
    const __bf16* b2p = cL + n * DIM + gh * 8;
    const float*  tp  = sBr + n;

    #pragma unroll 1
    for (int c = 0; c < NCHUNK; ++c) {
        const int off = c * (4 * 16 * DIM);
        float t[4]; bf16x8 B1[4], B2[4];
        #pragma unroll
        for (int q = 0; q < 4; ++q) {
            t[q]  = tp[c * 64 + q * 16];
            B1[q] = *(const bf16x8*)(b1p + off + q * (16 * DIM));
            B2[q] = *(const bf16x8*)(b2p + off + q * (16 * DIM));
        }
        f32x4 w[2];
        {
            f32x4 a0 = { t[0] - me[0][0], t[0] - me[0][1],
                         t[0] - me[0][2], t[0] - me[0][3] };
            a0 = __builtin_amdgcn_mfma_f32_16x16x32_bf16(A[0], B2[0], a0, 0, 0, 0);
            w[0] = __builtin_amdgcn_mfma_f32_16x16x32_bf16(A[0], B1[0], a0, 0, 0, 0);
        }
        #pragma unroll
        for (int k = 0; k < 16; ++k) {
            if (k < 15) {
                const int kn = k + 1, qn = kn >> 2, rn = kn & 3;
                f32x4 a = { t[qn] - me[rn][0], t[qn] - me[rn][1],
                            t[qn] - me[rn][2], t[qn] - me[rn][3] };
                a = __builtin_amdgcn_mfma_f32_16x16x32_bf16(A[rn], B2[qn], a, 0, 0, 0);
                w[kn & 1] = __builtin_amdgcn_mfma_f32_16x16x32_bf16(A[rn], B1[qn], a, 0, 0, 0);
            }
            const f32x4 wc = w[k & 1];
            const int rt = k & 3;
            const float h = fmaxf(fmaxf(wc[0], wc[1]), fmaxf(wc[2], wc[3]));
            if (__any(h > -win)) {
                s[rt][0] += fexp2(wc[0]);
                s[rt][1] += fexp2(wc[1]);
                s[rt][2] += fexp2(wc[2]);
                s[rt][3] += fexp2(wc[3]);
            }
        }
    }

    float lsum = 0.0f;
    float lse[RT][4];
    #pragma unroll
    for (int rt = 0; rt < RT; ++rt)
        #pragma unroll
        for (int e = 0; e < 4; ++e) {
            float ss = s[rt][e];
            #pragma unroll
            for (int d = 1; d < 16; d <<= 1)
                ss += __shfl_xor(ss, d, 64);
            ss = fmaxf(ss, 1.0e-30f);
            const float l = me[rt][e] + flog2(ss);
            lsum += l;
            lse[rt][e] = l;
        }

    write_msgs(lse, sBw, sM, sDmax, sDmin, wbase, lane);
    return lsum;
}

__global__ __launch_bounds__(THREADS)
void sinkhorn_kernel(const float* __restrict__ xg,
                     const float* __restrict__ yg,
                     float* __restrict__ out)
{
    extern __shared__ char ldsraw[];
    __bf16* sxh = (__bf16*)ldsraw;              // [1024][16] hi of K*x
    __bf16* sxl = sxh + NPTS * DIM;             // lo of K*x
    __bf16* syh = sxl + NPTS * DIM;             // hi of y
    __bf16* syl = syh + NPTS * DIM;             // lo of y
    float*  sBf  = (float*)(syl + NPTS * DIM);  // [1024] f-messages
    float*  sBg  = sBf + NPTS;                  // [1024] g-messages
    float*  sMf  = sBg + NPTS;                  // [1024] carried lse, f-rows
    float*  sMg  = sMf + NPTS;                  // [1024] carried lse, g-rows
    float*  sDmx = sMg + NPTS;                  // [64] drift max partials
    float*  sDmn = sDmx + 64;                   // [64] drift min partials

    const int tid   = threadIdx.x;
    const int lane  = tid & 63;
    const int wave  = tid >> 6;
    const int wbase = wave * (RT * 16);

    const int graph = blockIdx.x / 3;
    const int term  = blockIdx.x - graph * 3;   // 0:(x,y) 1:(x,x) 2:(y,y)
    const float* xb = xg + (size_t)graph * (NPTS * DIM);
    const float* yb = yg + (size_t)graph * (NPTS * DIM);
    const float* Xp = (term == 2) ? yb : xb;
    const float* Yp = (term == 1) ? xb : yb;

    split_store(sxh, sxl, Xp, KLOG, tid);       // row side carries the 1/eps scale
    split_store(syh, syl, Yp, 1.0f, tid);

    // quadratic terms (exact f32) + message init (thread = row)
    float csum;
    {
        const float hx = halfsq16(Xp + tid * DIM);
        const float hy = halfsq16(Yp + tid * DIM);
        csum = hx + hy;
        sBg[tid] = fmaf(-KLOG, hy, -10.0f);     // g-side messages for iter 0
        sBf[tid] = 0.0f;                        // finite placeholder (diff guard)
    }
    __syncthreads();

    float fsum = 0.0f, gsum = 0.0f;
    #pragma unroll 1
    for (int it = 0; it < NITERS; ++it) {
        if (it < NWARM) {
            fsum = warm_pass(sxh, sxl, syh, syl, sBg, sBf, sMf, sDmx, sDmn, wbase, lane);
            gsum = warm_pass(syh, syl, sxh, sxl, sBf, sBg, sMg, sDmx, sDmn, wbase, lane);
        } else {
            fsum = fused_pass(sxh, sxl, syh, syl, sBg, sBf, sMf, sDmx, sDmn, wbase, lane);
            gsum = fused_pass(syh, syl, sxh, sxl, sBf, sBg, sMg, sDmx, sDmn, wbase, lane);
        }
    }
    fsum = fused_pass(sxh, sxl, syh, syl, sBg, sBf, sMf, sDmx, sDmn, wbase, lane);

    // OT = [csum - CLSE*(sum lse_f + sum lse_g)] / NPTS  (lse sums x16 dup)
    float v = fmaf(-CLSE, (fsum + gsum) * (1.0f / 16.0f), csum);
    #pragma unroll
    for (int off = 32; off; off >>= 1) v += __shfl_down(v, off, 64);
    if (lane == 0) sBf[wave] = v;
    __syncthreads();
    if (tid == 0) {
        float tot = 0.0f;
        #pragma unroll
        for (int w = 0; w < NWAVES; ++w) tot += sBf[w];
        const float wgt = ((term == 0) ? 1.0f : -0.5f)
                          / ((float)GRAPHS * (float)NPTS);
        atomicAdd(out, wgt * tot);
    }
}

extern "C" void kernel_launch(void* const* d_in, const int* in_sizes, int n_in,
                              void* d_out, int out_size, void* d_ws, size_t ws_size,
                              hipStream_t stream)
{
    (void)in_sizes; (void)n_in; (void)d_ws; (void)ws_size; (void)out_size;
    const float* x = (const float*)d_in[0];
    const float* y = (const float*)d_in[1];
    float* out = (float*)d_out;

    constexpr size_t LDSB = 4 * NPTS * DIM * sizeof(__bf16)
                          + (4 * NPTS + 128) * sizeof(float);   // ~144.5 KiB
    hipFuncSetAttribute((const void*)sinkhorn_kernel,
                        hipFuncAttributeMaxDynamicSharedMemorySize, (int)LDSB);

    hipMemsetAsync(out, 0, sizeof(float), stream);
    hipLaunchKernelGGL(sinkhorn_kernel, dim3(GRAPHS * 3), dim3(THREADS), LDSB,
                       stream, x, y, out);
}